// Round 4
// baseline (153.072 us; speedup 1.0000x reference)
//
#include <hip/hip_runtime.h>

#define BB 32
#define NN 2048
#define DD 65
#define HH 64
#define ST 68                // padded leading dim (16B-aligned float4 frags)
#define TILE (DD * ST)       // 4420 floats per padded 65x65 matrix

__device__ __forceinline__ float4 f4add(float4 a, float4 b) {
  return make_float4(a.x + b.x, a.y + b.y, a.z + b.z, a.w + b.w);
}

// ---------------------------------------------------------------------------
// k1: partial Gram P[b][c] = (x chunk)^T (x chunk), 65x65, stride-68 tiles.
// 16x16 threads, 4x4 regs over the 64x64 core; ty==0 patches row/col 64 via
// symmetry. Staging: 17 batched loads in flight + cross-round pipeline.
// C=8 -> 256 blocks (1/CU), 4 rounds of 64 rows each.
// ---------------------------------------------------------------------------
__global__ __launch_bounds__(256) void k1_gram(const float* __restrict__ x,
                                               float* __restrict__ P,
                                               int C, int Rc) {
  __shared__ __align__(16) float Xl[64 * ST];
  const int t = (int)threadIdx.x;
  const int tx = t & 15, ty = t >> 4;
  const int blk = (int)blockIdx.x;
  const int b = blk / C, c = blk - b * C;
  const float* xb = x + ((size_t)b * NN + (size_t)c * Rc) * DD;

  float g[4][4] = {};
  float g64[4] = {};
  float gcc = 0.f;

  const int rounds = Rc >> 6;
  float tmp[17];
  {  // prefetch round 0 (17 independent loads in flight)
    const float* src = xb;
#pragma unroll
    for (int q = 0; q < 17; q++) {
      const int idx = t + 256 * q;
      if (idx < 64 * DD) tmp[q] = src[idx];
    }
  }
  for (int rd = 0; rd < rounds; rd++) {
#pragma unroll
    for (int q = 0; q < 17; q++) {
      const int idx = t + 256 * q;
      if (idx < 64 * DD) {
        const int r = idx / DD;
        Xl[r * ST + (idx - r * DD)] = tmp[q];
      }
    }
    __syncthreads();
    if (rd + 1 < rounds) {  // prefetch next round during compute
      const float* src = xb + (size_t)(rd + 1) * (64 * DD);
#pragma unroll
      for (int q = 0; q < 17; q++) {
        const int idx = t + 256 * q;
        if (idx < 64 * DD) tmp[q] = src[idx];
      }
    }
    for (int n = 0; n < 64; n++) {
      float rowf[4], colf[4];
      *(float4*)rowf = *(const float4*)&Xl[n * ST + 4 * ty];
      *(float4*)colf = *(const float4*)&Xl[n * ST + 4 * tx];
#pragma unroll
      for (int r = 0; r < 4; r++)
#pragma unroll
        for (int cc = 0; cc < 4; cc++)
          g[r][cc] = fmaf(rowf[r], colf[cc], g[r][cc]);
      if (ty == 0) {
        float x64 = Xl[n * ST + 64];
#pragma unroll
        for (int cc = 0; cc < 4; cc++) g64[cc] = fmaf(x64, colf[cc], g64[cc]);
        if (tx == 0) gcc = fmaf(x64, x64, gcc);
      }
    }
    __syncthreads();
  }
  float* Pp = P + (size_t)blk * TILE;
#pragma unroll
  for (int r = 0; r < 4; r++)
    *(float4*)&Pp[(4 * ty + r) * ST + 4 * tx] = *(float4*)g[r];
  if (ty == 0) {
    *(float4*)&Pp[64 * ST + 4 * tx] = *(float4*)g64;  // G[64][j]
#pragma unroll
    for (int cc = 0; cc < 4; cc++)
      Pp[(4 * tx + cc) * ST + 64] = g64[cc];          // G[i][64] by symmetry
    if (tx == 0) Pp[64 * ST + 64] = gcc;
  }
}

// ---------------------------------------------------------------------------
// k2: per batch: G = sum_c P; M = Wq^T Wk; R = M G; T = R Wv^T.
// P-reduction: explicit float4 batch loads + TREE sum -> C loads in flight
// per slot (the round-3 version compiled to a serialized load->add chain:
// 18 slots x 32 loads x ~220cyc = the whole 52us).
// ---------------------------------------------------------------------------
template <int C>
__global__ __launch_bounds__(256) void k2_chain(
    const float* __restrict__ Wq, const float* __restrict__ Wk,
    const float* __restrict__ Wv, const float* __restrict__ P,
    float* __restrict__ Tm) {
  __shared__ __align__(16) float A[TILE];
  __shared__ __align__(16) float Bf[TILE];
  const int t = (int)threadIdx.x;
  const int tx = t & 15, ty = t >> 4;
  const int b = (int)blockIdx.x;

  // phase 0: stage Wq -> A, Wk -> B (batched: 34 loads in flight)
  {
    float tq[17], tk[17];
#pragma unroll
    for (int q = 0; q < 17; q++) {
      const int idx = t + 256 * q;
      if (idx < HH * DD) { tq[q] = Wq[idx]; tk[q] = Wk[idx]; }
    }
#pragma unroll
    for (int q = 0; q < 17; q++) {
      const int idx = t + 256 * q;
      if (idx < HH * DD) {
        const int r = idx / DD, cc = idx - r * DD;
        A[r * ST + cc] = tq[q];
        Bf[r * ST + cc] = tk[q];
      }
    }
  }
  __syncthreads();

  // phase 1: M[i][j] = sum_h Wq[h][i] Wk[h][j] (in regs)
  float m[4][4] = {}, mrow[4] = {}, mcol[4] = {}, mcc = 0.f;
  for (int h = 0; h < HH; h++) {
    float qa[4], kb[4];
    *(float4*)qa = *(const float4*)&A[h * ST + 4 * ty];
    *(float4*)kb = *(const float4*)&Bf[h * ST + 4 * tx];
#pragma unroll
    for (int r = 0; r < 4; r++)
#pragma unroll
      for (int cc = 0; cc < 4; cc++) m[r][cc] = fmaf(qa[r], kb[cc], m[r][cc]);
    if (ty == 0) {
      float q64 = A[h * ST + 64];
#pragma unroll
      for (int cc = 0; cc < 4; cc++) mrow[cc] = fmaf(q64, kb[cc], mrow[cc]);
    }
    if (tx == 0) {
      float k64 = Bf[h * ST + 64];
#pragma unroll
      for (int r = 0; r < 4; r++) mcol[r] = fmaf(qa[r], k64, mcol[r]);
      if (ty == 0) mcc = fmaf(A[h * ST + 64], k64, mcc);
    }
  }
  __syncthreads();

  // phase 2: write M -> A; reduce P -> B (G) with float4 tree sum.
#pragma unroll
  for (int r = 0; r < 4; r++)
    *(float4*)&A[(4 * ty + r) * ST + 4 * tx] = *(float4*)m[r];
  if (ty == 0) *(float4*)&A[64 * ST + 4 * tx] = *(float4*)mrow;
  if (tx == 0) {
#pragma unroll
    for (int r = 0; r < 4; r++) A[(4 * ty + r) * ST + 64] = mcol[r];
  }
  if (t == 0) A[64 * ST + 64] = mcc;
  {
    const float4* Pb = (const float4*)(P + (size_t)b * C * TILE);
    const int Q = TILE / 4;  // 1105 float4 slots
#pragma unroll
    for (int q = 0; q < (TILE / 4 + 255) / 256; q++) {
      const int i4 = t + 256 * q;
      if (i4 < Q) {
        float4 v[C];
#pragma unroll
        for (int cc = 0; cc < C; cc++) v[cc] = Pb[(size_t)cc * Q + i4];
#pragma unroll
        for (int stp = C / 2; stp >= 1; stp >>= 1)
#pragma unroll
          for (int cc = 0; cc < stp; cc++) v[cc] = f4add(v[cc], v[cc + stp]);
        *((float4*)Bf + i4) = v[0];
      }
    }
  }
  __syncthreads();

  // phase 3: R[i][j] = sum_k M[i][k] G[k][j] (in regs)
  float rr[4][4] = {}, r64j[4] = {}, ri64[4] = {}, rcc = 0.f;
  for (int k = 0; k < DD; k++) {
    float gb[4], ma[4];
    *(float4*)gb = *(const float4*)&Bf[k * ST + 4 * tx];
#pragma unroll
    for (int r = 0; r < 4; r++) ma[r] = A[(4 * ty + r) * ST + k];
#pragma unroll
    for (int r = 0; r < 4; r++)
#pragma unroll
      for (int cc = 0; cc < 4; cc++)
        rr[r][cc] = fmaf(ma[r], gb[cc], rr[r][cc]);
    if (ty == 0) {
      float m64 = A[64 * ST + k];
#pragma unroll
      for (int cc = 0; cc < 4; cc++) r64j[cc] = fmaf(m64, gb[cc], r64j[cc]);
    }
    if (tx == 0) {
      float g64 = Bf[k * ST + 64];
#pragma unroll
      for (int r = 0; r < 4; r++) ri64[r] = fmaf(ma[r], g64, ri64[r]);
      if (ty == 0) rcc = fmaf(A[64 * ST + k], g64, rcc);
    }
  }
  __syncthreads();

  // phase 4: write R -> A; stage Wv^T -> B (batched)
#pragma unroll
  for (int r = 0; r < 4; r++)
    *(float4*)&A[(4 * ty + r) * ST + 4 * tx] = *(float4*)rr[r];
  if (ty == 0) *(float4*)&A[64 * ST + 4 * tx] = *(float4*)r64j;
  if (tx == 0) {
#pragma unroll
    for (int r = 0; r < 4; r++) A[(4 * ty + r) * ST + 64] = ri64[r];
  }
  if (t == 0) A[64 * ST + 64] = rcc;
  {
    float tv[17];
#pragma unroll
    for (int q = 0; q < 17; q++) {
      const int idx = t + 256 * q;
      if (idx < DD * DD) tv[q] = Wv[idx];
    }
#pragma unroll
    for (int q = 0; q < 17; q++) {
      const int idx = t + 256 * q;
      if (idx < DD * DD) {
        const int j = idx / DD, k = idx - j * DD;
        Bf[k * ST + j] = tv[q];
      }
    }
  }
  __syncthreads();

  // phase 5: T[i][j] = sum_k R[i][k] Wv[j][k]
  float tt[4][4] = {}, row64[4] = {}, col64[4] = {}, tcc = 0.f;
  for (int k = 0; k < DD; k++) {
    float wv[4], ra[4];
    *(float4*)wv = *(const float4*)&Bf[k * ST + 4 * tx];
#pragma unroll
    for (int ir = 0; ir < 4; ir++) ra[ir] = A[(4 * ty + ir) * ST + k];
#pragma unroll
    for (int ir = 0; ir < 4; ir++)
#pragma unroll
      for (int jc = 0; jc < 4; jc++)
        tt[ir][jc] = fmaf(ra[ir], wv[jc], tt[ir][jc]);
    if (ty == 0) {
      float r64 = A[64 * ST + k];
#pragma unroll
      for (int jc = 0; jc < 4; jc++) row64[jc] = fmaf(r64, wv[jc], row64[jc]);
    }
    if (tx == 0) {
      float w64 = Bf[k * ST + 64];
#pragma unroll
      for (int ir = 0; ir < 4; ir++) col64[ir] = fmaf(ra[ir], w64, col64[ir]);
      if (ty == 0) tcc = fmaf(A[64 * ST + k], w64, tcc);
    }
  }
  float* Tb = Tm + (size_t)b * TILE;
#pragma unroll
  for (int ir = 0; ir < 4; ir++)
    *(float4*)&Tb[(4 * ty + ir) * ST + 4 * tx] = *(float4*)tt[ir];
  if (ty == 0) *(float4*)&Tb[64 * ST + 4 * tx] = *(float4*)row64;  // T[64][j]
  if (tx == 0) {
#pragma unroll
    for (int ir = 0; ir < 4; ir++)
      Tb[(4 * ty + ir) * ST + 64] = col64[ir];                     // T[i][64]
  }
  if (t == 0) Tb[64 * ST + 64] = tcc;
}

// ---------------------------------------------------------------------------
// k3: out[b] = x[b] @ T[b]. 64 rows per block; T staged as pure float4 copy
// (identical padded layout in ws and LDS), x staged batched; 4x4 reg tiling.
// ---------------------------------------------------------------------------
__global__ __launch_bounds__(256) void k3_out(const float* __restrict__ x,
                                              const float* __restrict__ Tt,
                                              float* __restrict__ out) {
  __shared__ __align__(16) float Tl[TILE];
  __shared__ __align__(16) float Xl[64 * ST];
  const int t = (int)threadIdx.x;
  const int tx = t & 15, ty = t >> 4;
  const int blk = (int)blockIdx.x;
  const int b = blk >> 5;           // 32 blocks per batch
  const int rb = (blk & 31) * 64;
  const float4* Tg4 = (const float4*)(Tt + (size_t)b * TILE);
  const float* src = x + ((size_t)b * NN + rb) * DD;
  {
    float4 tT[5];
    float tX[17];
#pragma unroll
    for (int q = 0; q < 5; q++) {
      const int i4 = t + 256 * q;
      if (i4 < TILE / 4) tT[q] = Tg4[i4];
    }
#pragma unroll
    for (int q = 0; q < 17; q++) {
      const int idx = t + 256 * q;
      if (idx < 64 * DD) tX[q] = src[idx];
    }
#pragma unroll
    for (int q = 0; q < 5; q++) {
      const int i4 = t + 256 * q;
      if (i4 < TILE / 4) *((float4*)Tl + i4) = tT[q];
    }
#pragma unroll
    for (int q = 0; q < 17; q++) {
      const int idx = t + 256 * q;
      if (idx < 64 * DD) {
        const int r = idx / DD;
        Xl[r * ST + (idx - r * DD)] = tX[q];
      }
    }
  }
  __syncthreads();

  float o[4][4] = {}, o64[4] = {};
  for (int k = 0; k < DD; k++) {
    float xa[4], tb[4];
#pragma unroll
    for (int r = 0; r < 4; r++) xa[r] = Xl[(4 * ty + r) * ST + k];
    *(float4*)tb = *(const float4*)&Tl[k * ST + 4 * tx];
#pragma unroll
    for (int r = 0; r < 4; r++)
#pragma unroll
      for (int cc = 0; cc < 4; cc++) o[r][cc] = fmaf(xa[r], tb[cc], o[r][cc]);
    if (tx == 0) {
      float t64 = Tl[k * ST + 64];
#pragma unroll
      for (int r = 0; r < 4; r++) o64[r] = fmaf(xa[r], t64, o64[r]);
    }
  }
  float* ob = out + ((size_t)b * NN + rb) * DD;
#pragma unroll
  for (int r = 0; r < 4; r++)
#pragma unroll
    for (int cc = 0; cc < 4; cc++)
      ob[(4 * ty + r) * DD + 4 * tx + cc] = o[r][cc];
  if (tx == 0) {
#pragma unroll
    for (int r = 0; r < 4; r++) ob[(4 * ty + r) * DD + 64] = o64[r];
  }
}

extern "C" void kernel_launch(void* const* d_in, const int* in_sizes, int n_in,
                              void* d_out, int out_size, void* d_ws,
                              size_t ws_size, hipStream_t stream) {
  const float* x = (const float*)d_in[0];
  const float* Wq = (const float*)d_in[1];
  const float* Wk = (const float*)d_in[2];
  const float* Wv = (const float*)d_in[3];
  float* out = (float*)d_out;

  // Workspace: P[B*C] padded tiles + T[B] padded tiles. C=8 -> 5.1 MB.
  int C = 8;
  while (C > 1 && (size_t)(BB * C + BB) * TILE * sizeof(float) > ws_size)
    C >>= 1;
  const int Rc = NN / C;
  float* P = (float*)d_ws;
  float* Tm = P + (size_t)BB * C * TILE;

  k1_gram<<<BB * C, 256, 0, stream>>>(x, P, C, Rc);
  switch (C) {
    case 8:  k2_chain<8><<<BB, 256, 0, stream>>>(Wq, Wk, Wv, P, Tm); break;
    case 4:  k2_chain<4><<<BB, 256, 0, stream>>>(Wq, Wk, Wv, P, Tm); break;
    case 2:  k2_chain<2><<<BB, 256, 0, stream>>>(Wq, Wk, Wv, P, Tm); break;
    default: k2_chain<1><<<BB, 256, 0, stream>>>(Wq, Wk, Wv, P, Tm); break;
  }
  k3_out<<<BB * 32, 256, 0, stream>>>(x, Tm, out);
  (void)in_sizes; (void)n_in; (void)out_size; (void)ws_size;
}

// Round 5
// 147.194 us; speedup vs baseline: 1.0399x; 1.0399x over previous
//
#include <hip/hip_runtime.h>

#define BB 32
#define NN 2048
#define DD 65
#define HH 64
#define ST 68                // padded leading dim (16B-aligned float4 frags)
#define TILE (DD * ST)       // 4420 floats per padded 65x65 matrix
#define CC 32                // x chunks per batch (64 rows each)

__device__ __forceinline__ float4 f4add(float4 a, float4 b) {
  return make_float4(a.x + b.x, a.y + b.y, a.z + b.z, a.w + b.w);
}

// ---------------------------------------------------------------------------
// k1: partial Gram P[b][c] = (64-row x chunk)^T (chunk), 65x65 stride-68.
// C=32 -> 1024 blocks (4/CU: TLP hides LDS latency), single round.
// 16x16 threads, 4x4 regs over the 64x64 core; ty==0 patches row/col 64.
// ---------------------------------------------------------------------------
__global__ __launch_bounds__(256) void k1_gram(const float* __restrict__ x,
                                               float* __restrict__ P) {
  __shared__ __align__(16) float Xl[64 * ST];
  const int t = (int)threadIdx.x;
  const int tx = t & 15, ty = t >> 4;
  const int blk = (int)blockIdx.x;
  const int b = blk >> 5, c = blk & 31;
  const float* src = x + ((size_t)b * NN + (size_t)c * 64) * DD;

  {  // batched staging: 17 independent loads in flight
    float tmp[17];
#pragma unroll
    for (int q = 0; q < 17; q++) {
      const int idx = t + 256 * q;
      if (idx < 64 * DD) tmp[q] = src[idx];
    }
#pragma unroll
    for (int q = 0; q < 17; q++) {
      const int idx = t + 256 * q;
      if (idx < 64 * DD) {
        const int r = idx / DD;
        Xl[r * ST + (idx - r * DD)] = tmp[q];
      }
    }
  }
  __syncthreads();

  float g[4][4] = {};
  float g64[4] = {};
  float gcc = 0.f;
  for (int n = 0; n < 64; n++) {
    float rowf[4], colf[4];
    *(float4*)rowf = *(const float4*)&Xl[n * ST + 4 * ty];
    *(float4*)colf = *(const float4*)&Xl[n * ST + 4 * tx];
#pragma unroll
    for (int r = 0; r < 4; r++)
#pragma unroll
      for (int cc = 0; cc < 4; cc++)
        g[r][cc] = fmaf(rowf[r], colf[cc], g[r][cc]);
    if (ty == 0) {
      float x64 = Xl[n * ST + 64];
#pragma unroll
      for (int cc = 0; cc < 4; cc++) g64[cc] = fmaf(x64, colf[cc], g64[cc]);
      if (tx == 0) gcc = fmaf(x64, x64, gcc);
    }
  }
  float* Pp = P + (size_t)blk * TILE;
#pragma unroll
  for (int r = 0; r < 4; r++)
    *(float4*)&Pp[(4 * ty + r) * ST + 4 * tx] = *(float4*)g[r];
  if (ty == 0) {
    *(float4*)&Pp[64 * ST + 4 * tx] = *(float4*)g64;  // G[64][j]
#pragma unroll
    for (int cc = 0; cc < 4; cc++)
      Pp[(4 * tx + cc) * ST + 64] = g64[cc];          // G[i][64] by symmetry
    if (tx == 0) Pp[64 * ST + 64] = gcc;
  }
}

// ---------------------------------------------------------------------------
// kred: G[b] = sum over 32 chunk tiles of P[b]. 160 blocks (5 per batch),
// one float4 slot per thread, 8 loads in flight + tree sum (x4 groups).
// Fully parallel -- replaces the latency-bound reduction inside 32-block k2.
// ---------------------------------------------------------------------------
__global__ __launch_bounds__(256) void kred(const float* __restrict__ P,
                                            float* __restrict__ G) {
  const int t = (int)threadIdx.x;
  const int blk = (int)blockIdx.x;
  const int b = blk / 5, s = blk - b * 5;
  const int Q = TILE / 4;  // 1105
  const int i4 = s * 256 + t;
  if (i4 < Q) {
    const float4* Pb = (const float4*)(P + (size_t)b * CC * TILE);
    float4 acc = make_float4(0.f, 0.f, 0.f, 0.f);
#pragma unroll
    for (int grp = 0; grp < 4; grp++) {
      float4 v[8];
#pragma unroll
      for (int cc = 0; cc < 8; cc++)
        v[cc] = Pb[(size_t)(8 * grp + cc) * Q + i4];
#pragma unroll
      for (int stp = 4; stp >= 1; stp >>= 1)
#pragma unroll
        for (int cc = 0; cc < stp; cc++) v[cc] = f4add(v[cc], v[cc + stp]);
      acc = f4add(acc, v[0]);
    }
    ((float4*)(G + (size_t)b * TILE))[i4] = acc;
  }
}

// ---------------------------------------------------------------------------
// k2: per batch: M = Wq^T Wk; R = M G; T = R Wv^T. G comes pre-reduced from
// kred (vector-copy stage). 16x16 threads / 4x4 regs; edge patches for 64.
// ---------------------------------------------------------------------------
__global__ __launch_bounds__(256) void k2_chain(
    const float* __restrict__ Wq, const float* __restrict__ Wk,
    const float* __restrict__ Wv, const float* __restrict__ G,
    float* __restrict__ Tm) {
  __shared__ __align__(16) float A[TILE];
  __shared__ __align__(16) float Bf[TILE];
  const int t = (int)threadIdx.x;
  const int tx = t & 15, ty = t >> 4;
  const int b = (int)blockIdx.x;

  // phase 0: stage Wq -> A, Wk -> B (batched: 34 loads in flight)
  {
    float tq[17], tk[17];
#pragma unroll
    for (int q = 0; q < 17; q++) {
      const int idx = t + 256 * q;
      if (idx < HH * DD) { tq[q] = Wq[idx]; tk[q] = Wk[idx]; }
    }
#pragma unroll
    for (int q = 0; q < 17; q++) {
      const int idx = t + 256 * q;
      if (idx < HH * DD) {
        const int r = idx / DD, cc = idx - r * DD;
        A[r * ST + cc] = tq[q];
        Bf[r * ST + cc] = tk[q];
      }
    }
  }
  __syncthreads();

  // phase 1: M[i][j] = sum_h Wq[h][i] Wk[h][j] (in regs)
  float m[4][4] = {}, mrow[4] = {}, mcol[4] = {}, mcc = 0.f;
  for (int h = 0; h < HH; h++) {
    float qa[4], kb[4];
    *(float4*)qa = *(const float4*)&A[h * ST + 4 * ty];
    *(float4*)kb = *(const float4*)&Bf[h * ST + 4 * tx];
#pragma unroll
    for (int r = 0; r < 4; r++)
#pragma unroll
      for (int cc = 0; cc < 4; cc++) m[r][cc] = fmaf(qa[r], kb[cc], m[r][cc]);
    if (ty == 0) {
      float q64 = A[h * ST + 64];
#pragma unroll
      for (int cc = 0; cc < 4; cc++) mrow[cc] = fmaf(q64, kb[cc], mrow[cc]);
    }
    if (tx == 0) {
      float k64 = Bf[h * ST + 64];
#pragma unroll
      for (int r = 0; r < 4; r++) mcol[r] = fmaf(qa[r], k64, mcol[r]);
      if (ty == 0) mcc = fmaf(A[h * ST + 64], k64, mcc);
    }
  }
  __syncthreads();

  // phase 2: write M -> A; stage G -> B (pure float4 copy)
#pragma unroll
  for (int r = 0; r < 4; r++)
    *(float4*)&A[(4 * ty + r) * ST + 4 * tx] = *(float4*)m[r];
  if (ty == 0) *(float4*)&A[64 * ST + 4 * tx] = *(float4*)mrow;
  if (tx == 0) {
#pragma unroll
    for (int r = 0; r < 4; r++) A[(4 * ty + r) * ST + 64] = mcol[r];
  }
  if (t == 0) A[64 * ST + 64] = mcc;
  {
    const float4* Gb4 = (const float4*)(G + (size_t)b * TILE);
    float4 tG[5];
#pragma unroll
    for (int q = 0; q < 5; q++) {
      const int i4 = t + 256 * q;
      if (i4 < TILE / 4) tG[q] = Gb4[i4];
    }
#pragma unroll
    for (int q = 0; q < 5; q++) {
      const int i4 = t + 256 * q;
      if (i4 < TILE / 4) *((float4*)Bf + i4) = tG[q];
    }
  }
  __syncthreads();

  // phase 3: R[i][j] = sum_k M[i][k] G[k][j] (in regs)
  float rr[4][4] = {}, r64j[4] = {}, ri64[4] = {}, rcc = 0.f;
  for (int k = 0; k < DD; k++) {
    float gb[4], ma[4];
    *(float4*)gb = *(const float4*)&Bf[k * ST + 4 * tx];
#pragma unroll
    for (int r = 0; r < 4; r++) ma[r] = A[(4 * ty + r) * ST + k];
#pragma unroll
    for (int r = 0; r < 4; r++)
#pragma unroll
      for (int cc = 0; cc < 4; cc++)
        rr[r][cc] = fmaf(ma[r], gb[cc], rr[r][cc]);
    if (ty == 0) {
      float m64 = A[64 * ST + k];
#pragma unroll
      for (int cc = 0; cc < 4; cc++) r64j[cc] = fmaf(m64, gb[cc], r64j[cc]);
    }
    if (tx == 0) {
      float g64 = Bf[k * ST + 64];
#pragma unroll
      for (int r = 0; r < 4; r++) ri64[r] = fmaf(ma[r], g64, ri64[r]);
      if (ty == 0) rcc = fmaf(A[64 * ST + k], g64, rcc);
    }
  }
  __syncthreads();

  // phase 4: write R -> A; stage Wv^T -> B (batched)
#pragma unroll
  for (int r = 0; r < 4; r++)
    *(float4*)&A[(4 * ty + r) * ST + 4 * tx] = *(float4*)rr[r];
  if (ty == 0) *(float4*)&A[64 * ST + 4 * tx] = *(float4*)r64j;
  if (tx == 0) {
#pragma unroll
    for (int r = 0; r < 4; r++) A[(4 * ty + r) * ST + 64] = ri64[r];
  }
  if (t == 0) A[64 * ST + 64] = rcc;
  {
    float tv[17];
#pragma unroll
    for (int q = 0; q < 17; q++) {
      const int idx = t + 256 * q;
      if (idx < DD * DD) tv[q] = Wv[idx];
    }
#pragma unroll
    for (int q = 0; q < 17; q++) {
      const int idx = t + 256 * q;
      if (idx < DD * DD) {
        const int j = idx / DD, k = idx - j * DD;
        Bf[k * ST + j] = tv[q];
      }
    }
  }
  __syncthreads();

  // phase 5: T[i][j] = sum_k R[i][k] Wv[j][k]
  float tt[4][4] = {}, row64[4] = {}, col64[4] = {}, tcc = 0.f;
  for (int k = 0; k < DD; k++) {
    float wv[4], ra[4];
    *(float4*)wv = *(const float4*)&Bf[k * ST + 4 * tx];
#pragma unroll
    for (int ir = 0; ir < 4; ir++) ra[ir] = A[(4 * ty + ir) * ST + k];
#pragma unroll
    for (int ir = 0; ir < 4; ir++)
#pragma unroll
      for (int jc = 0; jc < 4; jc++)
        tt[ir][jc] = fmaf(ra[ir], wv[jc], tt[ir][jc]);
    if (ty == 0) {
      float r64 = A[64 * ST + k];
#pragma unroll
      for (int jc = 0; jc < 4; jc++) row64[jc] = fmaf(r64, wv[jc], row64[jc]);
    }
    if (tx == 0) {
      float w64 = Bf[k * ST + 64];
#pragma unroll
      for (int ir = 0; ir < 4; ir++) col64[ir] = fmaf(ra[ir], w64, col64[ir]);
      if (ty == 0) tcc = fmaf(A[64 * ST + k], w64, tcc);
    }
  }
  float* Tb = Tm + (size_t)b * TILE;
#pragma unroll
  for (int ir = 0; ir < 4; ir++)
    *(float4*)&Tb[(4 * ty + ir) * ST + 4 * tx] = *(float4*)tt[ir];
  if (ty == 0) *(float4*)&Tb[64 * ST + 4 * tx] = *(float4*)row64;  // T[64][j]
  if (tx == 0) {
#pragma unroll
    for (int ir = 0; ir < 4; ir++)
      Tb[(4 * ty + ir) * ST + 64] = col64[ir];                     // T[i][64]
  }
  if (t == 0) Tb[64 * ST + 64] = tcc;
}

// ---------------------------------------------------------------------------
// k3: out[b] = x[b] @ T[b]. 64 rows per block; T staged as pure float4 copy,
// x staged batched; 4x4 reg tiling; tx==0 patches output column 64.
// ---------------------------------------------------------------------------
__global__ __launch_bounds__(256) void k3_out(const float* __restrict__ x,
                                              const float* __restrict__ Tt,
                                              float* __restrict__ out) {
  __shared__ __align__(16) float Tl[TILE];
  __shared__ __align__(16) float Xl[64 * ST];
  const int t = (int)threadIdx.x;
  const int tx = t & 15, ty = t >> 4;
  const int blk = (int)blockIdx.x;
  const int b = blk >> 5;           // 32 blocks per batch
  const int rb = (blk & 31) * 64;
  const float4* Tg4 = (const float4*)(Tt + (size_t)b * TILE);
  const float* src = x + ((size_t)b * NN + rb) * DD;
  {
    float4 tT[5];
    float tX[17];
#pragma unroll
    for (int q = 0; q < 5; q++) {
      const int i4 = t + 256 * q;
      if (i4 < TILE / 4) tT[q] = Tg4[i4];
    }
#pragma unroll
    for (int q = 0; q < 17; q++) {
      const int idx = t + 256 * q;
      if (idx < 64 * DD) tX[q] = src[idx];
    }
#pragma unroll
    for (int q = 0; q < 5; q++) {
      const int i4 = t + 256 * q;
      if (i4 < TILE / 4) *((float4*)Tl + i4) = tT[q];
    }
#pragma unroll
    for (int q = 0; q < 17; q++) {
      const int idx = t + 256 * q;
      if (idx < 64 * DD) {
        const int r = idx / DD;
        Xl[r * ST + (idx - r * DD)] = tX[q];
      }
    }
  }
  __syncthreads();

  float o[4][4] = {}, o64[4] = {};
  for (int k = 0; k < DD; k++) {
    float xa[4], tb[4];
#pragma unroll
    for (int r = 0; r < 4; r++) xa[r] = Xl[(4 * ty + r) * ST + k];
    *(float4*)tb = *(const float4*)&Tl[k * ST + 4 * tx];
#pragma unroll
    for (int r = 0; r < 4; r++)
#pragma unroll
      for (int cc = 0; cc < 4; cc++) o[r][cc] = fmaf(xa[r], tb[cc], o[r][cc]);
    if (tx == 0) {
      float t64 = Tl[k * ST + 64];
#pragma unroll
      for (int r = 0; r < 4; r++) o64[r] = fmaf(xa[r], t64, o64[r]);
    }
  }
  float* ob = out + ((size_t)b * NN + rb) * DD;
#pragma unroll
  for (int r = 0; r < 4; r++)
#pragma unroll
    for (int cc = 0; cc < 4; cc++)
      ob[(4 * ty + r) * DD + 4 * tx + cc] = o[r][cc];
  if (tx == 0) {
#pragma unroll
    for (int r = 0; r < 4; r++) ob[(4 * ty + r) * DD + 64] = o64[r];
  }
}

extern "C" void kernel_launch(void* const* d_in, const int* in_sizes, int n_in,
                              void* d_out, int out_size, void* d_ws,
                              size_t ws_size, hipStream_t stream) {
  const float* x = (const float*)d_in[0];
  const float* Wq = (const float*)d_in[1];
  const float* Wk = (const float*)d_in[2];
  const float* Wv = (const float*)d_in[3];
  float* out = (float*)d_out;

  // Workspace: P[B*32 tiles] (18.1 MB) + G[B tiles] + T[B tiles] (~0.6 MB ea).
  float* P = (float*)d_ws;
  float* G = P + (size_t)BB * CC * TILE;
  float* Tm = G + (size_t)BB * TILE;

  k1_gram<<<BB * CC, 256, 0, stream>>>(x, P);
  kred<<<BB * 5, 256, 0, stream>>>(P, G);
  k2_chain<<<BB, 256, 0, stream>>>(Wq, Wk, Wv, G, Tm);
  k3_out<<<BB * CC, 256, 0, stream>>>(x, Tm, out);
  (void)in_sizes; (void)n_in; (void)out_size; (void)ws_size;
}